// Round 2
// 92.081 us; speedup vs baseline: 1.0972x; 1.0972x over previous
//
#include <hip/hip_runtime.h>
#include <cstdint>
#include <cstddef>

#define NTOT 8192
#define KTOT 256

typedef _Float16 half2v __attribute__((ext_vector_type(2)));
typedef _Float16 half8  __attribute__((ext_vector_type(8)));
typedef float floatx16 __attribute__((ext_vector_type(16)));

// ---- workspace layout (bytes) ----
// Triangular-packed B operand:
// jobs 0..159: paired-row triangle. step pp (0..31) pairs i_a=pp with i_b=63-pp,
//   5 chunks per step (pp<16: (i_a,c=0..3),(i_b,c=3); pp>=16: (i_a,c=1..3),(i_b,c=2..3))
// jobs 160..163: Sm tail (linear term).
// G_frag: [k32=8][job=164][lane=64][jj=8] f16
static constexpr int    NJOBS   = 164;
static constexpr size_t G_ELEMS = (size_t)8 * NJOBS * 64 * 8;    // 671,744 f16
static constexpr size_t OFF_CK  = G_ELEMS * 2;                   // 1,343,488
static constexpr size_t OFF_CTR = OFF_CK + 1024;                 // ctr(u32), facc(f32)
static constexpr size_t OFF_VAL = OFF_CK + 4096;                 // val2: [8192][4 by][2] f32 = 256 KB

__device__ __forceinline__ uint16_t f2h(float x) {
  _Float16 h = (_Float16)x;
  return __builtin_bit_cast(uint16_t, h);
}

// A-frag: 8 f16 = s2 * rp[0..3]  (4 x v_pk_mul_f16)
__device__ __forceinline__ half8 mkh(half2v s, const half2v* rp) {
  union { half2v p[4]; half8 v; } u;
  u.p[0] = s * rp[0]; u.p[1] = s * rp[1]; u.p[2] = s * rp[2]; u.p[3] = s * rp[3];
  return u.v;
}
__device__ __forceinline__ half8 cph(const half2v* rp) {
  union { half2v p[4]; half8 v; } u;
  u.p[0] = rp[0]; u.p[1] = rp[1]; u.p[2] = rp[2]; u.p[3] = rp[3];
  return u.v;
}

// ---------------- P1: per-k prep (incl. redundant log_softmax). 1 block/k ----
__global__ void p1_prep(const float* __restrict__ means, const float* __restrict__ diag,
                        const float* __restrict__ tri, const float* __restrict__ weigh,
                        uint16_t* __restrict__ Gf, float* __restrict__ ck,
                        unsigned int* __restrict__ ctr, float* __restrict__ facc) {
  int k = blockIdx.x;
  int t = threadIdx.x;
  __shared__ float lv[64], ms[64], bv64[64], wred[256];
  __shared__ float Wp[64][68];   // stride 68: float4-aligned, rotating banks
  __shared__ float SS[64][65];   // stride 65: conflict-free scalar columns
  __shared__ float lse_s;

  // zero the k3 finish counter/accumulator (workspace is poisoned each iter)
  if (k == 0 && t == 0) { *ctr = 0u; *facc = 0.f; }

  // log_softmax denominator over all 256 weights
  float wv = weigh[t];
  wred[t] = wv; __syncthreads();
  for (int o = 128; o > 0; o >>= 1) { if (t < o) wred[t] = fmaxf(wred[t], wred[t + o]); __syncthreads(); }
  float wm = wred[0]; __syncthreads();
  wred[t] = __expf(wv - wm); __syncthreads();
  for (int o = 128; o > 0; o >>= 1) { if (t < o) wred[t] += wred[t + o]; __syncthreads(); }
  if (t == 0) lse_s = wm + __logf(wred[0]);

  float logdet0 = 0.f;   // valid in lane 0 of wave 0 after shuffle
  if (t < 64) {
    float d = diag[k * 64 + t];
    float l = tanhf(d);
    lv[t] = l;
    ms[t] = means[k * 64 + t];
    float ld = __logf(fabsf(l));
    #pragma unroll
    for (int o = 32; o > 0; o >>= 1) ld += __shfl_xor(ld, o);
    logdet0 = ld;
  }
  __syncthreads();

  // build W' = (I + strict_lower(tri)) * diag(lv)
  for (int e = 0; e < 16; ++e) {
    int idx = e * 256 + t;
    int i = idx >> 6, c = idx & 63;
    float L = (c < i) ? tri[k * 4096 + idx] : 0.f;
    float w = ((c == i) ? 1.f : 0.f) + L;
    Wp[i][c] = w * lv[c];
  }
  __syncthreads();

  // S = W'^T W' : each thread a 4x4 tile
  int i0 = (t >> 4) * 4, j0 = (t & 15) * 4;
  float acc[4][4];
  #pragma unroll
  for (int a = 0; a < 4; ++a)
    #pragma unroll
    for (int b = 0; b < 4; ++b) acc[a][b] = 0.f;
  for (int r = 0; r < 64; ++r) {
    float4 av = *(const float4*)&Wp[r][i0];
    float4 bv = *(const float4*)&Wp[r][j0];
    float aa[4] = {av.x, av.y, av.z, av.w};
    float bb[4] = {bv.x, bv.y, bv.z, bv.w};
    #pragma unroll
    for (int a = 0; a < 4; ++a)
      #pragma unroll
      for (int b = 0; b < 4; ++b) acc[a][b] = fmaf(aa[a], bb[b], acc[a][b]);
  }
  #pragma unroll
  for (int a = 0; a < 4; ++a)
    #pragma unroll
    for (int b = 0; b < 4; ++b) SS[i0 + a][j0 + b] = acc[a][b];
  __syncthreads();

  // bv = S m  (conflict-free: SS stride 65), msm via shuffle
  if (t < 64) {
    float b = 0.f;
    for (int j = 0; j < 64; ++j) b = fmaf(SS[t][j], ms[j], b);
    bv64[t] = b;
    float bm = b * ms[t];
    #pragma unroll
    for (int o = 32; o > 0; o >>= 1) bm += __shfl_xor(bm, o);
    if (t == 0) ck[k] = logdet0 + (weigh[k] - lse_s) - 0.5f * bm;
  }
  __syncthreads();

  // Triangular store: 328 half-chunks (160 tri jobs * 2 halves + 8 tail halves).
  // hc<320: job = hc>>1, half = hc&1; decode job -> (i, c) matching K2 consumption:
  //   pp = job/5, q = job%5
  //   pp<16 : q<4 -> (i=pp,   c=q)      ; q==4 -> (i=63-pp, c=3)
  //   pp>=16: q<3 -> (i=pp,   c=q+1)    ; q>=3 -> (i=63-pp, c=q-1)
  // values: j<i -> 0, j==i -> -0.5*S_ii, j>i -> -S_ij (symmetric fold, exact x2 in f16)
  int k32 = k >> 5, kl = k & 31;
  for (int hc = t; hc < 328; hc += 256) {
    float v[8];
    int job, half = hc & 1;
    if (hc < 320) {
      job = hc >> 1;
      int pp = job / 5, q = job - pp * 5;
      int i, c;
      if (pp < 16) { if (q < 4) { i = pp; c = q; } else { i = 63 - pp; c = 3; } }
      else         { if (q < 3) { i = pp; c = q + 1; } else { i = 63 - pp; c = q - 1; } }
      int jb = c * 16 + half * 8;
      #pragma unroll
      for (int e = 0; e < 8; ++e) {
        int j = jb + e;
        float s = SS[i][j];
        v[e] = (j < i) ? 0.f : ((j == i) ? -0.5f * s : -s);
      }
    } else {
      job = 160 + ((hc - 320) >> 1);
      int b0 = (hc - 320) * 8;
      #pragma unroll
      for (int e = 0; e < 8; ++e) v[e] = bv64[b0 + e];
    }
    uint4 pk;
    pk.x = (uint32_t)f2h(v[0]) | ((uint32_t)f2h(v[1]) << 16);
    pk.y = (uint32_t)f2h(v[2]) | ((uint32_t)f2h(v[3]) << 16);
    pk.z = (uint32_t)f2h(v[4]) | ((uint32_t)f2h(v[5]) << 16);
    pk.w = (uint32_t)f2h(v[6]) | ((uint32_t)f2h(v[7]) << 16);
    size_t base = ((size_t)(k32 * NJOBS + job) * 64 + half * 32 + kl) * 8;
    *(uint4*)(Gf + base) = pk;
  }
}

// ---------------- K2: MFMA GEMM, triangular-K per block, fused partial-LSE ---
// grid (64, 4): bx = 128-row block, by = 64-col block. 4 waves:
// wave (wn,wk) = 64 rows x 32 cols, 2 row-tiles of 32 (MFMA 32x32x16 f16).
// Triangular k-dim: 32 paired steps x 5 chunks + 4 Sm tail jobs. 4-step ring prefetch.
// Epilogue: val2[n][by] = (m, sumexp) over this block's 64 cols (ck included).
__launch_bounds__(256)
__global__ void k2_gemm(const float* __restrict__ x, const uint16_t* __restrict__ Gf,
                        const float* __restrict__ ck, float* __restrict__ val2) {
  __shared__ float xl[128][65];
  int t = threadIdx.x;
  int bx = blockIdx.x, by = blockIdx.y;
  const float* xblk = x + (size_t)bx * (128 * 64);

  for (int e = 0; e < 8; ++e) {
    int lin = e * 1024 + t * 4;
    float4 v = *(const float4*)(xblk + lin);
    int r = lin >> 6, c = lin & 63;
    xl[r][c] = v.x; xl[r][c + 1] = v.y; xl[r][c + 2] = v.z; xl[r][c + 3] = v.w;
  }
  __syncthreads();

  int wave = t >> 6, l = t & 63;
  int wn = wave >> 1, wk = wave & 1;
  int half = l >> 5, lane31 = l & 31;
  int r0 = wn * 64 + lane31, r1 = r0 + 32;

  // per-lane x runs in packed f16: row r, chunks c*16 + half*8 .. +7
  half2v runh0[4][4], runh1[4][4];
  #pragma unroll
  for (int c = 0; c < 4; ++c) {
    int base = c * 16 + half * 8;
    float4 ra = *(const float4*)(xblk + (size_t)r0 * 64 + base);
    float4 rb = *(const float4*)(xblk + (size_t)r0 * 64 + base + 4);
    runh0[c][0][0] = (_Float16)ra.x; runh0[c][0][1] = (_Float16)ra.y;
    runh0[c][1][0] = (_Float16)ra.z; runh0[c][1][1] = (_Float16)ra.w;
    runh0[c][2][0] = (_Float16)rb.x; runh0[c][2][1] = (_Float16)rb.y;
    runh0[c][3][0] = (_Float16)rb.z; runh0[c][3][1] = (_Float16)rb.w;
    float4 rc = *(const float4*)(xblk + (size_t)r1 * 64 + base);
    float4 rd = *(const float4*)(xblk + (size_t)r1 * 64 + base + 4);
    runh1[c][0][0] = (_Float16)rc.x; runh1[c][0][1] = (_Float16)rc.y;
    runh1[c][1][0] = (_Float16)rc.z; runh1[c][1][1] = (_Float16)rc.w;
    runh1[c][2][0] = (_Float16)rd.x; runh1[c][2][1] = (_Float16)rd.y;
    runh1[c][3][0] = (_Float16)rd.z; runh1[c][3][1] = (_Float16)rd.w;
  }

  int k32 = by * 2 + wk;
  const uint4* Bp = (const uint4*)Gf;
  size_t bofs = (size_t)(k32 * NJOBS) * 64 + l;

  floatx16 acc0, acc1;
  #pragma unroll
  for (int i = 0; i < 16; ++i) { acc0[i] = 0.f; acc1[i] = 0.f; }

  // prologue: steps 0..3 into ring slots 0..3 (slot = step & 3)
  uint4 bufs[4][5];
  #pragma unroll
  for (int s = 0; s < 4; ++s)
    #pragma unroll
    for (int q = 0; q < 5; ++q) bufs[s][q] = Bp[bofs + (size_t)(s * 5 + q) * 64];

  // Loop A: pp = 0..15, pair (i_a=pp, c=0..3) + (i_b=63-pp, c=3)
  #pragma unroll
  for (int pp = 0; pp < 16; ++pp) {
    const int s = pp & 3;
    float xa0f = xl[r0][pp],      xa1f = xl[r1][pp];
    float xb0f = xl[r0][63 - pp], xb1f = xl[r1][63 - pp];
    _Float16 ha0 = (_Float16)xa0f; half2v ya0; ya0[0] = ha0; ya0[1] = ha0;
    _Float16 ha1 = (_Float16)xa1f; half2v ya1; ya1[0] = ha1; ya1[1] = ha1;
    _Float16 hb0 = (_Float16)xb0f; half2v yb0; yb0[0] = hb0; yb0[1] = hb0;
    _Float16 hb1 = (_Float16)xb1f; half2v yb1; yb1[0] = hb1; yb1[1] = hb1;
    #pragma unroll
    for (int c = 0; c < 4; ++c) {
      half8 a0 = mkh(ya0, runh0[c]);
      half8 a1 = mkh(ya1, runh1[c]);
      half8 bb = __builtin_bit_cast(half8, bufs[s][c]);
      acc0 = __builtin_amdgcn_mfma_f32_32x32x16_f16(a0, bb, acc0, 0, 0, 0);
      acc1 = __builtin_amdgcn_mfma_f32_32x32x16_f16(a1, bb, acc1, 0, 0, 0);
    }
    {
      half8 a0 = mkh(yb0, runh0[3]);
      half8 a1 = mkh(yb1, runh1[3]);
      half8 bb = __builtin_bit_cast(half8, bufs[s][4]);
      acc0 = __builtin_amdgcn_mfma_f32_32x32x16_f16(a0, bb, acc0, 0, 0, 0);
      acc1 = __builtin_amdgcn_mfma_f32_32x32x16_f16(a1, bb, acc1, 0, 0, 0);
    }
    #pragma unroll
    for (int q = 0; q < 5; ++q)
      bufs[s][q] = Bp[bofs + (size_t)((pp + 4) * 5 + q) * 64];
  }

  // Loop B: pp = 16..31, pair (i_a=pp, c=1..3) + (i_b=63-pp, c=2..3)
  #pragma unroll
  for (int pp = 16; pp < 32; ++pp) {
    const int s = pp & 3;
    float xa0f = xl[r0][pp],      xa1f = xl[r1][pp];
    float xb0f = xl[r0][63 - pp], xb1f = xl[r1][63 - pp];
    _Float16 ha0 = (_Float16)xa0f; half2v ya0; ya0[0] = ha0; ya0[1] = ha0;
    _Float16 ha1 = (_Float16)xa1f; half2v ya1; ya1[0] = ha1; ya1[1] = ha1;
    _Float16 hb0 = (_Float16)xb0f; half2v yb0; yb0[0] = hb0; yb0[1] = hb0;
    _Float16 hb1 = (_Float16)xb1f; half2v yb1; yb1[0] = hb1; yb1[1] = hb1;
    #pragma unroll
    for (int c = 1; c < 4; ++c) {
      half8 a0 = mkh(ya0, runh0[c]);
      half8 a1 = mkh(ya1, runh1[c]);
      half8 bb = __builtin_bit_cast(half8, bufs[s][c - 1]);
      acc0 = __builtin_amdgcn_mfma_f32_32x32x16_f16(a0, bb, acc0, 0, 0, 0);
      acc1 = __builtin_amdgcn_mfma_f32_32x32x16_f16(a1, bb, acc1, 0, 0, 0);
    }
    #pragma unroll
    for (int c = 2; c < 4; ++c) {
      half8 a0 = mkh(yb0, runh0[c]);
      half8 a1 = mkh(yb1, runh1[c]);
      half8 bb = __builtin_bit_cast(half8, bufs[s][c + 1]);
      acc0 = __builtin_amdgcn_mfma_f32_32x32x16_f16(a0, bb, acc0, 0, 0, 0);
      acc1 = __builtin_amdgcn_mfma_f32_32x32x16_f16(a1, bb, acc1, 0, 0, 0);
    }
    if (pp <= 27) {   // prefetch steps 20..31; step 32 (tail) prefetched below
      #pragma unroll
      for (int q = 0; q < 5; ++q)
        bufs[s][q] = Bp[bofs + (size_t)((pp + 4) * 5 + q) * 64];
    } else if (pp == 28) {
      // step 32 = tail jobs 160..163 only (4 chunks; no job 164 — stay in Gf)
      #pragma unroll
      for (int q = 0; q < 4; ++q)
        bufs[s][q] = Bp[bofs + (size_t)(160 + q) * 64];
    }
  }

  // tail: jobs 160..163 (Sm features, A = raw x) — step 32 lives in slot 0
  #pragma unroll
  for (int c = 0; c < 4; ++c) {
    half8 a0 = cph(runh0[c]);
    half8 a1 = cph(runh1[c]);
    half8 bb = __builtin_bit_cast(half8, bufs[0][c]);
    acc0 = __builtin_amdgcn_mfma_f32_32x32x16_f16(a0, bb, acc0, 0, 0, 0);
    acc1 = __builtin_amdgcn_mfma_f32_32x32x16_f16(a1, bb, acc1, 0, 0, 0);
  }

  // epilogue: stash val (+ck) into xl (reuse), then per-row partial LSE
  __syncthreads();
  float ckv = ck[by * 64 + wk * 32 + lane31];
  #pragma unroll
  for (int reg = 0; reg < 16; ++reg) {
    int row = (reg & 3) + 8 * (reg >> 2) + 4 * half;
    xl[wn * 64 + row][wk * 32 + lane31] = acc0[reg] + ckv;
    xl[wn * 64 + 32 + row][wk * 32 + lane31] = acc1[reg] + ckv;
  }
  __syncthreads();
  if (t < 128) {
    float m = -3.0e38f;
    #pragma unroll
    for (int j = 0; j < 64; ++j) m = fmaxf(m, xl[t][j]);
    float s = 0.f;
    #pragma unroll
    for (int j = 0; j < 64; ++j) s += __expf(xl[t][j] - m);
    size_t n = (size_t)bx * 128 + t;
    val2[n * 8 + by * 2 + 0] = m;
    val2[n * 8 + by * 2 + 1] = s;
  }
}

// ---------------- K3: combine 4 (m,s) pairs per row -> lse, atomic finish ----
__global__ void k3_lse(const float* __restrict__ val2, float* __restrict__ facc,
                       unsigned int* __restrict__ ctr, float* __restrict__ out) {
  __shared__ float red[4];
  int t = threadIdx.x;
  size_t n = (size_t)blockIdx.x * 256 + t;
  const float4* p = (const float4*)(val2 + n * 8);
  float4 a = p[0], b = p[1];
  float M = fmaxf(fmaxf(a.x, a.z), fmaxf(b.x, b.z));
  float s = a.y * __expf(a.x - M) + a.w * __expf(a.z - M) +
            b.y * __expf(b.x - M) + b.w * __expf(b.z - M);
  float lse = M + __logf(s);
  #pragma unroll
  for (int o = 32; o > 0; o >>= 1) lse += __shfl_xor(lse, o);
  if ((t & 63) == 0) red[t >> 6] = lse;
  __syncthreads();
  if (t == 0) {
    float part = red[0] + red[1] + red[2] + red[3];
    atomicAdd(facc, part);           // device-scope, coherent point
    __threadfence();                 // order facc-add before ctr-add
    unsigned int rank = atomicAdd(ctr, 1u);
    if (rank == 31) {                // last of 32 blocks: all adds visible
      float total = atomicAdd(facc, 0.0f);   // coherent read
      out[0] = 58.8120661251f - total / 8192.0f;  // 32*log(2*pi) - mean(lse)
    }
  }
}

extern "C" void kernel_launch(void* const* d_in, const int* in_sizes, int n_in,
                              void* d_out, int out_size, void* d_ws, size_t ws_size,
                              hipStream_t stream) {
  const float* x     = (const float*)d_in[0];
  const float* means = (const float*)d_in[1];
  const float* diag  = (const float*)d_in[2];
  const float* tri   = (const float*)d_in[3];
  const float* weigh = (const float*)d_in[4];

  char* ws = (char*)d_ws;
  uint16_t* Gf       = (uint16_t*)ws;
  float* ck          = (float*)(ws + OFF_CK);
  unsigned int* ctr  = (unsigned int*)(ws + OFF_CTR);
  float* facc        = (float*)(ws + OFF_CTR + 4);
  float* val2        = (float*)(ws + OFF_VAL);

  p1_prep<<<dim3(256), dim3(256), 0, stream>>>(means, diag, tri, weigh, Gf, ck, ctr, facc);
  k2_gemm<<<dim3(64, 4), dim3(256), 0, stream>>>(x, Gf, ck, val2);
  k3_lse<<<dim3(32), dim3(256), 0, stream>>>(val2, facc, ctr, (float*)d_out);
}